// Round 14
// baseline (356.937 us; speedup 1.0000x reference)
//
#include <hip/hip_runtime.h>
#include <stdint.h>
#include <stddef.h>

#define NHEADS 16
#define QLORA  1536
#define KVLORA 512
#define QKH    192
#define VH     128
#define BB     2
#define SS     1024
#define MROWS  (BB*SS)   // 2048
#define HID    3072

typedef __attribute__((ext_vector_type(4))) float fx4;
typedef __attribute__((ext_vector_type(4))) short sx4;
typedef __attribute__((ext_vector_type(8))) short sx8;

__device__ __forceinline__ short f2bf(float f) {
  uint32_t u = __builtin_bit_cast(uint32_t, f);
  u = (u + 0x7fffu + ((u >> 16) & 1u)) >> 16;
  return (short)u;
}
__device__ __forceinline__ float bf2f(short s) {
  uint32_t u = ((uint32_t)(uint16_t)s) << 16;
  return __builtin_bit_cast(float, u);
}
__device__ __forceinline__ void gl_lds16(const void* g, void* l) {
  __builtin_amdgcn_global_load_lds((const __attribute__((address_space(1))) void*)g,
                                   (__attribute__((address_space(3))) void*)l, 16, 0, 0);
}
__device__ __forceinline__ sx8 ldfrag(const short* p) {
  sx4 lo = *(const sx4*)p;
  sx4 hi = *(const sx4*)(p + 16);
  sx8 r;
  r[0]=lo[0]; r[1]=lo[1]; r[2]=lo[2]; r[3]=lo[3];
  r[4]=hi[0]; r[5]=hi[1]; r[6]=hi[2]; r[7]=hi[3];
  return r;
}
// 8-chunk-row swizzled LDS fragment load (BK=64 rows): chunk c of row stored
// at (c&~7)|((c&7)^(row&7)).
__device__ __forceinline__ sx8 ldfrag_swz(const short* lds, int row, int rowShorts,
                                          int baseChunk, int g) {
  const int r7 = row & 7;
  const int gh = g >> 1, lo4 = (g & 1) * 4;
  int ch0 = baseChunk + gh;
  int ch1 = baseChunk + 2 + gh;
  ch0 = (ch0 & ~7) | ((ch0 & 7) ^ r7);
  ch1 = (ch1 & ~7) | ((ch1 & 7) ^ r7);
  const short* base = lds + row * rowShorts;
  sx4 a = *(const sx4*)(base + ch0 * 8 + lo4);
  sx4 b = *(const sx4*)(base + ch1 * 8 + lo4);
  sx8 r;
  r[0]=a[0]; r[1]=a[1]; r[2]=a[2]; r[3]=a[3];
  r[4]=b[0]; r[5]=b[1]; r[6]=b[2]; r[7]=b[3];
  return r;
}
// BK=32-row swizzled fragment load (R5/R6-proven): 4 chunks/row, chunk c at
// c^((row>>1)&3). Fragment k = {4g..4g+3} (chunk g>>1), {16+4g..} (chunk 2+(g>>1)).
__device__ __forceinline__ sx8 ldfrag_swz32(const short* lds, int row, int g) {
  const int f = (row >> 1) & 3;
  const int c0 = (g >> 1) ^ f;
  const int c1 = (2 + (g >> 1)) ^ f;
  const int lo4 = (g & 1) * 4;
  const short* base = lds + row * 32;
  sx4 a = *(const sx4*)(base + c0 * 8 + lo4);
  sx4 b = *(const sx4*)(base + c1 * 8 + lo4);
  sx8 r;
  r[0]=a[0]; r[1]=a[1]; r[2]=a[2]; r[3]=a[3];
  r[4]=b[0]; r[5]=b[1]; r[6]=b[2]; r[7]=b[3];
  return r;
}

struct CvtSeg { const float* src; short* dst; int n4; };
__device__ __forceinline__ void cvt_one(const CvtSeg& sg, int i) {
  fx4 v = *(const fx4*)(sg.src + (size_t)i * 4);
  sx4 o;
  o[0] = f2bf(v[0]); o[1] = f2bf(v[1]); o[2] = f2bf(v[2]); o[3] = f2bf(v[3]);
  *(sx4*)(sg.dst + (size_t)i * 4) = o;
}

// ---------------- cvt {hs, wqa, wkva} (blocks 0..1023) + rope table tail ----
__global__ void k_cvt3(CvtSeg s0, CvtSeg s1, CvtSeg s2, float* __restrict__ tab) {
  if ((int)blockIdx.x >= 1024) {
    int i = ((int)blockIdx.x - 1024) * 256 + threadIdx.x;   // < 32768
    if (i < SS * 32) {
      int pos = i >> 5, fi = i & 31;
      float inv = powf(10000.0f, -(float)fi / 32.0f);
      float ang = (float)pos * inv;
      tab[i * 2]     = cosf(ang);
      tab[i * 2 + 1] = sinf(ang);
    }
    return;
  }
  const CvtSeg segs[3] = {s0, s1, s2};
  const int stride = 1024 * 256;
  const int t0 = blockIdx.x * 256 + threadIdx.x;
#pragma unroll
  for (int s = 0; s < 3; ++s)
    for (int i = t0; i < segs[s].n4; i += stride) cvt_one(segs[s], i);
}

// -------- dual-problem GEMM, 2-phase dbuf BK=32, (MFR*32) x 128 tile --------
// SPLITK==1: C = A·Bt^T + bias (bf16 out).  SPLITK>1: bf16 partials at
// C + pi*2048*N, no bias.  Tail blocks (>= nbGemm) run cvt segments c0/c1.
// 2-phase: STAGE(next) issued BEFORE compute of current tile; one
// __syncthreads per K-step drains vmcnt+lgkm (R6-proven sync structure).
struct GemmProb {
  const short* A; const short* Bt; const float* bias; void* C;
  int N; int K;
};

template <int MFR, int SPLITK>
__global__ __launch_bounds__(256, 3)
void k_gemmS(GemmProb p0, GemmProb p1, int nblk0, int nbGemm,
             CvtSeg c0, CvtSeg c1) {
  if ((int)blockIdx.x >= nbGemm) {
    const int nthr = ((int)gridDim.x - nbGemm) * 256;
    const int t0 = ((int)blockIdx.x - nbGemm) * 256 + threadIdx.x;
    if (c0.src) for (int i = t0; i < c0.n4; i += nthr) cvt_one(c0, i);
    if (c1.src) for (int i = t0; i < c1.n4; i += nthr) cvt_one(c1, i);
    return;
  }
  constexpr int TM = MFR * 32;
  constexpr int MT = 2048 / TM;        // m-tiles
  int bid = ((int)blockIdx.x % 8) * (nbGemm >> 3) + ((int)blockIdx.x >> 3);
  const GemmProb p = (bid < nblk0) ? p0 : p1;
  int lb = (bid < nblk0) ? bid : bid - nblk0;
  const int N = p.N, K = p.K;
  const int NT = (N + 127) >> 7;
  const int tiles = MT * NT;
  const int tile = lb % tiles;
  const int pi = (SPLITK > 1) ? (lb / tiles) : 0;
  const int m0 = (tile % MT) * TM;
  const int n0 = (tile / MT) * 128;
  const int Kc = K / SPLITK;
  const int k0 = pi * Kc;

  __shared__ short As[2][TM * 32];     // MFR=8: 2 x 16 KB
  __shared__ short Bs[2][128 * 32];    // 2 x 8 KB
  const int tid  = threadIdx.x;
  const int lane = tid & 63;
  const int g    = lane >> 4;
  const int r16  = lane & 15;
  const int wave = tid >> 6;
  const int wm   = (wave >> 1) * (TM / 2);
  const int wn   = (wave & 1) * 64;

  fx4 acc[MFR][4] = {};

  // A: TM*4 chunks (MFR/2 rounds of 256), B: 512 chunks (2 rounds)
#define STAGE(bufi, kk)                                                        \
  do {                                                                         \
    _Pragma("unroll")                                                          \
    for (int i = 0; i < MFR / 2; ++i) {                                        \
      int cc = tid + 256 * i;                                                  \
      int row = cc >> 2;                                                       \
      int sc = ((cc & 3) ^ (row >> 1)) & 3;                                    \
      gl_lds16(p.A + (size_t)(m0 + row) * K + (kk) + sc * 8,                   \
               &As[bufi][cc * 8]);                                             \
    }                                                                          \
    _Pragma("unroll")                                                          \
    for (int i = 0; i < 2; ++i) {                                              \
      int cc = tid + 256 * i;                                                  \
      int row = cc >> 2;                                                       \
      int sc = ((cc & 3) ^ (row >> 1)) & 3;                                    \
      int bn = n0 + row; if (bn > N - 1) bn = N - 1;                           \
      gl_lds16(p.Bt + (size_t)bn * K + (kk) + sc * 8, &Bs[bufi][cc * 8]);      \
    }                                                                          \
  } while (0)

  const int nk = Kc >> 5;
  STAGE(0, k0);
  __syncthreads();

  int cur = 0;
  for (int t = 0; t < nk; ++t) {
    if (t + 1 < nk) STAGE(cur ^ 1, k0 + (t + 1) * 32);
    {
      sx8 bfv[4];
#pragma unroll
      for (int ni = 0; ni < 4; ++ni)
        bfv[ni] = ldfrag_swz32(&Bs[cur][0], wn + ni * 16 + r16, g);
#pragma unroll
      for (int mi = 0; mi < MFR; ++mi) {
        sx8 af = ldfrag_swz32(&As[cur][0], wm + mi * 16 + r16, g);
#pragma unroll
        for (int ni = 0; ni < 4; ++ni)
          acc[mi][ni] = __builtin_amdgcn_mfma_f32_16x16x32_bf16(af, bfv[ni], acc[mi][ni], 0, 0, 0);
      }
    }
    __syncthreads();   // drains vmcnt(0)+lgkmcnt(0): next tile landed, reads done
    cur ^= 1;
  }
#undef STAGE

  if (SPLITK > 1) {
    short* Cp = (short*)p.C + (size_t)pi * 2048 * N;
#pragma unroll
    for (int mi = 0; mi < MFR; ++mi) {
      int mbase = m0 + wm + mi * 16 + 4 * g;
#pragma unroll
      for (int ni = 0; ni < 4; ++ni) {
        int ncol = n0 + wn + ni * 16 + r16;
        if (ncol < N) {
#pragma unroll
          for (int r = 0; r < 4; ++r)
            Cp[(size_t)(mbase + r) * N + ncol] = f2bf(acc[mi][ni][r]);
        }
      }
    }
  } else {
#pragma unroll
    for (int mi = 0; mi < MFR; ++mi) {
      int mbase = m0 + wm + mi * 16 + 4 * g;
#pragma unroll
      for (int ni = 0; ni < 4; ++ni) {
        int ncol = n0 + wn + ni * 16 + r16;
        if (ncol < N) {
          float bv = p.bias[ncol];
#pragma unroll
          for (int r = 0; r < 4; ++r)
            ((short*)p.C)[(size_t)(mbase + r) * N + ncol] = f2bf(acc[mi][ni][r] + bv);
        }
      }
    }
  }
}

// ---------------- fused prep: split-K reduce (bf16) + bias + norms + rope_k -
__global__ __launch_bounds__(256)
void k_prep(const short* __restrict__ qp, const float* __restrict__ q_bias,
            const float* __restrict__ q_norm_w, short* __restrict__ qn,
            const short* __restrict__ kvp, const float* __restrict__ kv_bias,
            const float* __restrict__ kv_norm_w, short* __restrict__ kvn,
            short* __restrict__ kr, const float* __restrict__ tab) {
  const int row = blockIdx.x;
  const int t = threadIdx.x;
  const size_t QS = (size_t)2048 * QLORA;
  const size_t KS = (size_t)2048 * 576;

  float x[8];
  float s1 = 0.f, s2 = 0.f;
  if (t < 192) {
    const short* a = qp + (size_t)row * QLORA + t * 8;
    sx8 u = *(const sx8*)(a);
    sx8 v = *(const sx8*)(a + QS);
    sx8 w = *(const sx8*)(a + 2 * QS);
#pragma unroll
    for (int j = 0; j < 8; ++j) {
      x[j] = bf2f(u[j]) + bf2f(v[j]) + bf2f(w[j]) + q_bias[t * 8 + j];
      s1 += x[j] * x[j];
    }
  } else {
    const int c = t - 192;
    const short* a = kvp + (size_t)row * 576 + c * 8;
    sx8 u = *(const sx8*)(a);
    sx8 v = *(const sx8*)(a + KS);
    sx8 w = *(const sx8*)(a + 2 * KS);
#pragma unroll
    for (int j = 0; j < 8; ++j) {
      x[j] = bf2f(u[j]) + bf2f(v[j]) + bf2f(w[j]) + kv_bias[c * 8 + j];
      s2 += x[j] * x[j];
    }
  }
#pragma unroll
  for (int o = 32; o >= 1; o >>= 1) {
    s1 += __shfl_xor(s1, o, 64);
    s2 += __shfl_xor(s2, o, 64);
  }
  __shared__ float r1[4], r2[4];
  if ((t & 63) == 0) { r1[t >> 6] = s1; r2[t >> 6] = s2; }
  __syncthreads();
  float qss = r1[0] + r1[1] + r1[2] + r1[3];
  float kss = r2[0] + r2[1] + r2[2] + r2[3];
  float qrs = 1.0f / sqrtf(qss / (float)QLORA + 1e-6f);
  float krs = 1.0f / sqrtf(kss / (float)KVLORA + 1e-6f);

  if (t < 192) {
    sx8 o;
#pragma unroll
    for (int j = 0; j < 8; ++j) o[j] = f2bf(x[j] * qrs * q_norm_w[t * 8 + j]);
    *(sx8*)(qn + (size_t)row * QLORA + t * 8) = o;
  } else {
    int c = t - 192;
    sx8 o;
#pragma unroll
    for (int j = 0; j < 8; ++j) o[j] = f2bf(x[j] * krs * kv_norm_w[c * 8 + j]);
    *(sx8*)(kvn + (size_t)row * KVLORA + c * 8) = o;
  }
  if (t < 8) {
    const short* a = kvp + (size_t)row * 576 + 512 + t * 8;
    sx8 u = *(const sx8*)(a);
    sx8 v = *(const sx8*)(a + KS);
    sx8 w = *(const sx8*)(a + 2 * KS);
    float y[8];
#pragma unroll
    for (int j = 0; j < 8; ++j)
      y[j] = bf2f(u[j]) + bf2f(v[j]) + bf2f(w[j]) + kv_bias[512 + t * 8 + j];
    int pos = row & (SS - 1);
    sx8 o;
#pragma unroll
    for (int k = 0; k < 4; ++k) {
      int i = t * 4 + k;
      float c = tab[(pos * 32 + i) * 2], s = tab[(pos * 32 + i) * 2 + 1];
      o[2 * k]     = f2bf(y[2 * k] * c - y[2 * k + 1] * s);
      o[2 * k + 1] = f2bf(y[2 * k] * s + y[2 * k + 1] * c);
    }
    *(sx8*)(kr + (size_t)row * 64 + t * 8) = o;
  }
}

// ---------------- fused post: V-transpose (blocks 0..511) + rope_q ----------
__global__ __launch_bounds__(256)
void k_post(const short* __restrict__ kvb, short* __restrict__ vt,
            short* __restrict__ qb, const float* __restrict__ tab) {
  const int bid = blockIdx.x;
  const int tid = threadIdx.x;
  if (bid < 512) {
    const int bh = bid >> 4;
    const int t0 = (bid & 15) * 64;
    const int b = bh >> 4, h = bh & 15;
    __shared__ short sm[64 * 128];
#pragma unroll
    for (int i = 0; i < 4; ++i) {
      int c = tid + 256 * i;
      int tt = c >> 4, d0 = (c & 15) * 8;
      sx8 v = *(const sx8*)(kvb + ((size_t)(b * SS + t0 + tt)) * 4096 + h * 256 + 128 + d0);
      *(sx8*)(sm + tt * 128 + d0) = v;
    }
    __syncthreads();
#pragma unroll
    for (int i = 0; i < 4; ++i) {
      int c = tid + 256 * i;
      int d = c >> 3, tof = (c & 7) * 8;
      sx8 v;
#pragma unroll
      for (int j = 0; j < 8; ++j) v[j] = sm[(tof + j) * 128 + d];
      *(sx8*)(vt + ((size_t)bh * VH + d) * SS + t0 + tof) = v;
    }
  } else {
    int p = (bid - 512) * 256 + tid;
    int j = p & 7, h = (p >> 3) & 15, row = p >> 7;
    int pos = row & (SS - 1);
    size_t base = (((size_t)row * NHEADS + h) * QKH) + 128 + j * 8;
    sx8 x = *(const sx8*)(qb + base);
    sx8 o;
#pragma unroll
    for (int k = 0; k < 4; ++k) {
      int i = j * 4 + k;
      float c = tab[(pos * 32 + i) * 2], s = tab[(pos * 32 + i) * 2 + 1];
      float x1 = bf2f(x[2 * k]), x2 = bf2f(x[2 * k + 1]);
      o[2 * k]     = f2bf(x1 * c - x2 * s);
      o[2 * k + 1] = f2bf(x1 * s + x2 * c);
    }
    *(sx8*)(qb + base) = o;
  }
}

// ---------------- wo split-K reduce (bf16 partials): out = p0 + p1 + bias ---
__global__ __launch_bounds__(256)
void k_osum(const short* __restrict__ p, const float* __restrict__ bias,
            float* __restrict__ out) {
  const size_t OS = (size_t)2048 * HID;
  int i = blockIdx.x * 256 + threadIdx.x;          // 8-elem chunk index
  sx8 a = *(const sx8*)(p + (size_t)i * 8);
  sx8 b = *(const sx8*)(p + OS + (size_t)i * 8);
  int col = (i * 8) % HID;
  fx4 o0, o1;
#pragma unroll
  for (int j = 0; j < 4; ++j) {
    o0[j] = bf2f(a[j]) + bf2f(b[j]) + bias[col + j];
    o1[j] = bf2f(a[4 + j]) + bf2f(b[4 + j]) + bias[col + 4 + j];
  }
  *(fx4*)(out + (size_t)i * 8) = o0;
  *(fx4*)(out + (size_t)i * 8 + 4) = o1;
}

// ---------------- fused causal attention (balanced q-tile permutation) ------
__global__ __launch_bounds__(256, 2)
void k_attn(const short* __restrict__ q, const short* __restrict__ kvb,
            const short* __restrict__ kr, const short* __restrict__ vt,
            short* __restrict__ ao) {
  const int bh = blockIdx.x;
  const int b = bh >> 4, h = bh & 15;
  const int py = blockIdx.y;
  const int qi = (py < 8) ? py : 23 - py;
  const int qt0 = qi * 64;
  const int tid = threadIdx.x;
  const int lane = tid & 63;
  const int wave = tid >> 6;
  const int g = lane >> 4, r16 = lane & 15;
  const int qg = qt0 + wave * 16 + r16;

  __shared__ short Ks[64 * QKH];
  __shared__ short Vs[VH * 64];

  sx8 qf[6];
  {
    const short* qr = q + (((size_t)(b * SS + qg)) * NHEADS + h) * QKH;
#pragma unroll
    for (int f = 0; f < 6; ++f) qf[f] = ldfrag(qr + f * 32 + 4 * g);
  }

  float mrun = -1e30f, lrun = 0.0f;
  fx4 oacc[8] = {};
  const float scale = 0.07216878364870323f;

  const int ntiles = qt0 / 64 + 1;
  for (int kt = 0; kt < ntiles; ++kt) {
    const int t0 = kt * 64;
#pragma unroll
    for (int i = 0; i < 6; ++i) {
      int cc = tid + 256 * i;
      int row = cc / 24, ch = cc % 24;
      int sc = (ch & 24) | ((ch & 7) ^ (row & 7));
      size_t grow = (size_t)(b * SS + t0 + row);
      const short* src = (sc < 16) ? kvb + grow * 4096 + h * 256 + sc * 8
                                   : kr + grow * 64 + (sc - 16) * 8;
      gl_lds16(src, &Ks[cc * 8]);
    }
#pragma unroll
    for (int i = 0; i < 4; ++i) {
      int cc = tid + 256 * i;
      int row = cc >> 3;
      int sc = (cc & 7) ^ (row & 7);
      gl_lds16(vt + ((size_t)bh * VH + row) * SS + t0 + sc * 8, &Vs[cc * 8]);
    }
    __syncthreads();

    const bool diag = (kt == ntiles - 1);
    float pv[16];
    float tmax = -1e30f;
#pragma unroll
    for (int th = 0; th < 4; ++th) {
      fx4 sacc = {};
#pragma unroll
      for (int f = 0; f < 6; ++f) {
        sx8 kf = ldfrag_swz(Ks, th * 16 + r16, QKH, f * 4, g);
        sacc = __builtin_amdgcn_mfma_f32_16x16x32_bf16(kf, qf[f], sacc, 0, 0, 0);
      }
#pragma unroll
      for (int r = 0; r < 4; ++r) {
        int t = t0 + th * 16 + 4 * g + r;
        float s = sacc[r] * scale;
        if (diag && t > qg) s = -1e30f;
        pv[th * 4 + r] = s;
        tmax = fmaxf(tmax, s);
      }
    }
    tmax = fmaxf(tmax, __shfl_xor(tmax, 16, 64));
    tmax = fmaxf(tmax, __shfl_xor(tmax, 32, 64));
    float mnew = fmaxf(mrun, tmax);
    float corr = __expf(mrun - mnew);
    float psum = 0.f;
#pragma unroll
    for (int j = 0; j < 16; ++j) { pv[j] = __expf(pv[j] - mnew); psum += pv[j]; }
    psum += __shfl_xor(psum, 16, 64);
    psum += __shfl_xor(psum, 32, 64);
    lrun = lrun * corr + psum;
    mrun = mnew;
#pragma unroll
    for (int f8 = 0; f8 < 8; ++f8) oacc[f8] *= corr;

    sx8 pf0, pf1;
#pragma unroll
    for (int j = 0; j < 8; ++j) { pf0[j] = f2bf(pv[j]); pf1[j] = f2bf(pv[8 + j]); }

#pragma unroll
    for (int f8 = 0; f8 < 8; ++f8) {
      sx8 v0 = ldfrag_swz(Vs, f8 * 16 + r16, 64, 0, g);
      sx8 v1 = ldfrag_swz(Vs, f8 * 16 + r16, 64, 4, g);
      oacc[f8] = __builtin_amdgcn_mfma_f32_16x16x32_bf16(v0, pf0, oacc[f8], 0, 0, 0);
      oacc[f8] = __builtin_amdgcn_mfma_f32_16x16x32_bf16(v1, pf1, oacc[f8], 0, 0, 0);
    }
    __syncthreads();
  }

  float inv = 1.0f / lrun;
#pragma unroll
  for (int f8 = 0; f8 < 8; ++f8)
#pragma unroll
    for (int r = 0; r < 4; ++r) {
      int d = f8 * 16 + 4 * g + r;
      ao[(((size_t)(b * SS + qg)) * NHEADS + h) * VH + d] = f2bf(oacc[f8][r] * inv);
    }
}

// ---------------- launcher ----------------
extern "C" void kernel_launch(void* const* d_in, const int* in_sizes, int n_in,
                              void* d_out, int out_size, void* d_ws, size_t ws_size,
                              hipStream_t stream) {
  const float* hs       = (const float*)d_in[0];
  const float* wq_a_w   = (const float*)d_in[2];
  const float* wq_a_b   = (const float*)d_in[3];
  const float* q_norm_w = (const float*)d_in[4];
  const float* wq_b_w   = (const float*)d_in[5];
  const float* wq_b_b   = (const float*)d_in[6];
  const float* wkv_a_w  = (const float*)d_in[7];
  const float* wkv_a_b  = (const float*)d_in[8];
  const float* kv_norm_w= (const float*)d_in[9];
  const float* wkv_b_w  = (const float*)d_in[10];
  const float* wkv_b_b  = (const float*)d_in[11];
  const float* wo_w     = (const float*)d_in[12];
  const float* wo_b     = (const float*)d_in[13];
  float* out = (float*)d_out;

  short* ws0 = (short*)d_ws;
  size_t off = 0;
  short* wqa_bf  = ws0 + off; off += (size_t)QLORA * HID;
  short* wqb_bf  = ws0 + off; off += (size_t)HID * QLORA;
  short* wkva_bf = ws0 + off; off += (size_t)576 * HID;
  short* wkvb_bf = ws0 + off; off += (size_t)4096 * KVLORA;
  short* wo_bf   = ws0 + off; off += (size_t)HID * 2048;
  short* h_bf    = ws0 + off; off += (size_t)MROWS * HID;
  short* qn      = ws0 + off; off += (size_t)MROWS * QLORA;
  short* kvn     = ws0 + off; off += (size_t)MROWS * KVLORA;
  short* kr      = ws0 + off; off += (size_t)MROWS * 64;
  short* qb      = ws0 + off; off += (size_t)MROWS * HID;
  short* kvb     = ws0 + off; off += (size_t)MROWS * 4096;
  short* vtb     = ws0 + off; off += (size_t)BB * NHEADS * VH * SS;
  short* ao      = ws0 + off; off += (size_t)MROWS * 2048;
  float* tab     = (float*)(ws0 + off + (off & 1));
  // bf16 partial arena (time-shared: a-GEMM partials, then wo partials)
  short* arena   = (short*)(tab + SS * 64);
  short* qlatp   = arena;                                  // [3][2048][1536] bf16
  short* kvp     = arena + (size_t)3 * 2048 * QLORA;       // [3][2048][576] bf16
  short* wop     = arena;                                  // [2][2048][3072] bf16

  // 1) cvt {hs, wqa, wkva} + rope table (one launch)
  {
    CvtSeg s0{hs,      h_bf,    (int)((size_t)MROWS * HID / 4)};
    CvtSeg s1{wq_a_w,  wqa_bf,  (int)((size_t)QLORA * HID / 4)};
    CvtSeg s2{wkv_a_w, wkva_bf, (int)((size_t)576 * HID / 4)};
    k_cvt3<<<1024 + 128, 256, 0, stream>>>(s0, s1, s2, tab);
  }

  // 2) merged a-GEMM splitK3 (bf16 partials) + tail cvt of {wqb, wkvb}
  {
    GemmProb pq{h_bf, wqa_bf,  nullptr, qlatp, QLORA, HID};
    GemmProb pk{h_bf, wkva_bf, nullptr, kvp,   576,   HID};
    int nb0 = 8 * (QLORA / 128) * 3;         // 288
    int nb1 = 8 * ((576 + 127) / 128) * 3;   // 120
    int nbG = nb0 + nb1;                     // 408
    CvtSeg c0{wq_b_w,  wqb_bf,  (int)((size_t)HID * QLORA / 4)};
    CvtSeg c1{wkv_b_w, wkvb_bf, (int)((size_t)4096 * KVLORA / 4)};
    k_gemmS<8, 3><<<nbG + 192, 256, 0, stream>>>(pq, pk, nb0, nbG, c0, c1);
  }

  // 3) fused split-K reduce + bias + norms + rope_k
  k_prep<<<MROWS, 256, 0, stream>>>(qlatp, wq_a_b, q_norm_w, qn,
                                    kvp, wkv_a_b, kv_norm_w, kvn, kr, tab);

  // 4) merged b-GEMM + tail cvt of {wo}
  {
    GemmProb pq{qn,  wqb_bf,  wq_b_b,  qb,  HID,  QLORA};
    GemmProb pk{kvn, wkvb_bf, wkv_b_b, kvb, 4096, KVLORA};
    int nb0 = 8 * (HID / 128);               // 192
    int nb1 = 8 * (4096 / 128);              // 256
    int nbG = nb0 + nb1;                     // 448
    CvtSeg c0{wo_w, wo_bf, (int)((size_t)HID * 2048 / 4)};
    CvtSeg c1{nullptr, nullptr, 0};
    k_gemmS<8, 1><<<nbG + 192, 256, 0, stream>>>(pq, pk, nb0, nbG, c0, c1);
  }

  // 5) fused V-transpose + rope_q
  k_post<<<512 + 1024, 256, 0, stream>>>(kvb, vtb, qb, tab);

  // 6) attention (balanced causal work)
  k_attn<<<dim3(BB * NHEADS, SS / 64), 256, 0, stream>>>(qb, kvb, kr, vtb, ao);

  // 7) output projection, split-K x2 (bf16 partials) + fused bias-reduce
  {
    GemmProb po{ao, wo_bf, nullptr, wop, HID, 2048};
    int nb = 8 * (HID / 128) * 2;            // 384
    CvtSeg cz{nullptr, nullptr, 0};
    k_gemmS<8, 2><<<nb, 256, 0, stream>>>(po, po, nb, nb, cz, cz);
  }
  k_osum<<<(MROWS * HID / 8) / 256, 256, 0, stream>>>(wop, wo_b, out);
}

// Round 15
// 223.312 us; speedup vs baseline: 1.5984x; 1.5984x over previous
//
#include <hip/hip_runtime.h>
#include <stdint.h>
#include <stddef.h>

#define NHEADS 16
#define QLORA  1536
#define KVLORA 512
#define QKH    192
#define VH     128
#define BB     2
#define SS     1024
#define MROWS  (BB*SS)   // 2048
#define HID    3072

typedef __attribute__((ext_vector_type(4))) float fx4;
typedef __attribute__((ext_vector_type(4))) short sx4;
typedef __attribute__((ext_vector_type(8))) short sx8;

__device__ __forceinline__ short f2bf(float f) {
  uint32_t u = __builtin_bit_cast(uint32_t, f);
  u = (u + 0x7fffu + ((u >> 16) & 1u)) >> 16;
  return (short)u;
}
__device__ __forceinline__ float bf2f(short s) {
  uint32_t u = ((uint32_t)(uint16_t)s) << 16;
  return __builtin_bit_cast(float, u);
}
__device__ __forceinline__ void gl_lds16(const void* g, void* l) {
  __builtin_amdgcn_global_load_lds((const __attribute__((address_space(1))) void*)g,
                                   (__attribute__((address_space(3))) void*)l, 16, 0, 0);
}
__device__ __forceinline__ sx8 ldfrag(const short* p) {
  sx4 lo = *(const sx4*)p;
  sx4 hi = *(const sx4*)(p + 16);
  sx8 r;
  r[0]=lo[0]; r[1]=lo[1]; r[2]=lo[2]; r[3]=lo[3];
  r[4]=hi[0]; r[5]=hi[1]; r[6]=hi[2]; r[7]=hi[3];
  return r;
}
// 8-chunk-row swizzled LDS fragment load: chunk c of row stored at
// (c&~7)|((c&7)^(row&7)).  rowShorts = row pitch in shorts.
__device__ __forceinline__ sx8 ldfrag_swz(const short* lds, int row, int rowShorts,
                                          int baseChunk, int g) {
  const int r7 = row & 7;
  const int gh = g >> 1, lo4 = (g & 1) * 4;
  int ch0 = baseChunk + gh;
  int ch1 = baseChunk + 2 + gh;
  ch0 = (ch0 & ~7) | ((ch0 & 7) ^ r7);
  ch1 = (ch1 & ~7) | ((ch1 & 7) ^ r7);
  const short* base = lds + row * rowShorts;
  sx4 a = *(const sx4*)(base + ch0 * 8 + lo4);
  sx4 b = *(const sx4*)(base + ch1 * 8 + lo4);
  sx8 r;
  r[0]=a[0]; r[1]=a[1]; r[2]=a[2]; r[3]=a[3];
  r[4]=b[0]; r[5]=b[1]; r[6]=b[2]; r[7]=b[3];
  return r;
}

struct CvtSeg { const float* src; short* dst; int n4; };
__device__ __forceinline__ void cvt_one(const CvtSeg& sg, int i) {
  fx4 v = *(const fx4*)(sg.src + (size_t)i * 4);
  sx4 o;
  o[0] = f2bf(v[0]); o[1] = f2bf(v[1]); o[2] = f2bf(v[2]); o[3] = f2bf(v[3]);
  *(sx4*)(sg.dst + (size_t)i * 4) = o;
}

// ---------------- cvt {hs, wqa, wkva} (blocks 0..1023) + rope table tail ----
__global__ void k_cvt3(CvtSeg s0, CvtSeg s1, CvtSeg s2, float* __restrict__ tab) {
  if ((int)blockIdx.x >= 1024) {
    int i = ((int)blockIdx.x - 1024) * 256 + threadIdx.x;   // < 32768
    if (i < SS * 32) {
      int pos = i >> 5, fi = i & 31;
      float inv = powf(10000.0f, -(float)fi / 32.0f);
      float ang = (float)pos * inv;
      tab[i * 2]     = cosf(ang);
      tab[i * 2 + 1] = sinf(ang);
    }
    return;
  }
  const CvtSeg segs[3] = {s0, s1, s2};
  const int stride = 1024 * 256;
  const int t0 = blockIdx.x * 256 + threadIdx.x;
#pragma unroll
  for (int s = 0; s < 3; ++s)
    for (int i = t0; i < segs[s].n4; i += stride) cvt_one(segs[s], i);
}

// ---------------- dual-problem GEMM, single-buffer BK=64, (MFR*32) x 128 ----
// SPLITK==1: C = A·Bt^T + bias (bf16 out).  SPLITK>1: bf16 partials at
// C + pi*2048*N, no bias.  Tail blocks (>= nbGemm) run cvt segments c0/c1
// (independent work filling GEMM latency-stall idle BW).
struct GemmProb {
  const short* A; const short* Bt; const float* bias; void* C;
  int N; int K;
};

template <int MFR, int SPLITK>
__global__ __launch_bounds__(256, 2)
void k_gemmS(GemmProb p0, GemmProb p1, int nblk0, int nbGemm,
             CvtSeg c0, CvtSeg c1) {
  if ((int)blockIdx.x >= nbGemm) {
    const int nthr = ((int)gridDim.x - nbGemm) * 256;
    const int t0 = ((int)blockIdx.x - nbGemm) * 256 + threadIdx.x;
    if (c0.src) for (int i = t0; i < c0.n4; i += nthr) cvt_one(c0, i);
    if (c1.src) for (int i = t0; i < c1.n4; i += nthr) cvt_one(c1, i);
    return;
  }
  constexpr int TM = MFR * 32;
  constexpr int MT = 2048 / TM;        // m-tiles
  int bid = ((int)blockIdx.x % 8) * (nbGemm >> 3) + ((int)blockIdx.x >> 3);
  const GemmProb p = (bid < nblk0) ? p0 : p1;
  int lb = (bid < nblk0) ? bid : bid - nblk0;
  const int N = p.N, K = p.K;
  const int NT = (N + 127) >> 7;
  const int tiles = MT * NT;
  const int tile = lb % tiles;
  const int pi = (SPLITK > 1) ? (lb / tiles) : 0;
  const int m0 = (tile % MT) * TM;
  const int n0 = (tile / MT) * 128;
  const int Kc = K / SPLITK;
  const int k0 = pi * Kc;

  __shared__ short As[TM * 64];    // MFR=8: 32 KB
  __shared__ short Bs[128 * 64];   // 16 KB
  const int tid  = threadIdx.x;
  const int lane = tid & 63;
  const int g    = lane >> 4;
  const int r16  = lane & 15;
  const int wave = tid >> 6;
  const int wm   = (wave >> 1) * (TM / 2);
  const int wn   = (wave & 1) * 64;

  fx4 acc[MFR][4] = {};

  for (int kk = k0; kk < k0 + Kc; kk += 64) {
#pragma unroll
    for (int i = 0; i < MFR; ++i) {
      int cc  = tid + 256 * i;
      int row = cc >> 3;
      int src = ((cc & 7) ^ (row & 7)) * 8;
      gl_lds16(p.A + (size_t)(m0 + row) * K + kk + src, &As[cc * 8]);
    }
#pragma unroll
    for (int i = 0; i < 4; ++i) {
      int cc  = tid + 256 * i;
      int row = cc >> 3;
      int src = ((cc & 7) ^ (row & 7)) * 8;
      int bn = n0 + row; if (bn > N - 1) bn = N - 1;
      gl_lds16(p.Bt + (size_t)bn * K + kk + src, &Bs[cc * 8]);
    }
    __syncthreads();

#pragma unroll
    for (int s = 0; s < 2; ++s) {
      sx8 bfv[4];
#pragma unroll
      for (int ni = 0; ni < 4; ++ni)
        bfv[ni] = ldfrag_swz(Bs, wn + ni * 16 + r16, 64, s * 4, g);
#pragma unroll
      for (int mi = 0; mi < MFR; ++mi) {
        sx8 af = ldfrag_swz(As, wm + mi * 16 + r16, 64, s * 4, g);
#pragma unroll
        for (int ni = 0; ni < 4; ++ni)
          acc[mi][ni] = __builtin_amdgcn_mfma_f32_16x16x32_bf16(af, bfv[ni], acc[mi][ni], 0, 0, 0);
      }
    }
    __syncthreads();
  }

  if (SPLITK > 1) {
    short* Cp = (short*)p.C + (size_t)pi * 2048 * N;
#pragma unroll
    for (int mi = 0; mi < MFR; ++mi) {
      int mbase = m0 + wm + mi * 16 + 4 * g;
#pragma unroll
      for (int ni = 0; ni < 4; ++ni) {
        int ncol = n0 + wn + ni * 16 + r16;
        if (ncol < N) {
#pragma unroll
          for (int r = 0; r < 4; ++r)
            Cp[(size_t)(mbase + r) * N + ncol] = f2bf(acc[mi][ni][r]);
        }
      }
    }
  } else {
#pragma unroll
    for (int mi = 0; mi < MFR; ++mi) {
      int mbase = m0 + wm + mi * 16 + 4 * g;
#pragma unroll
      for (int ni = 0; ni < 4; ++ni) {
        int ncol = n0 + wn + ni * 16 + r16;
        if (ncol < N) {
          float bv = p.bias[ncol];
#pragma unroll
          for (int r = 0; r < 4; ++r)
            ((short*)p.C)[(size_t)(mbase + r) * N + ncol] = f2bf(acc[mi][ni][r] + bv);
        }
      }
    }
  }
}

// ---------------- fused prep: split-K reduce (bf16) + bias + norms + rope_k -
// qp: [3][2048][1536] bf16 partials; kvp: [3][2048][576] bf16 partials.
__global__ __launch_bounds__(256)
void k_prep(const short* __restrict__ qp, const float* __restrict__ q_bias,
            const float* __restrict__ q_norm_w, short* __restrict__ qn,
            const short* __restrict__ kvp, const float* __restrict__ kv_bias,
            const float* __restrict__ kv_norm_w, short* __restrict__ kvn,
            short* __restrict__ kr, const float* __restrict__ tab) {
  const int row = blockIdx.x;
  const int t = threadIdx.x;
  const size_t QS = (size_t)2048 * QLORA;
  const size_t KS = (size_t)2048 * 576;

  float x[8];
  float s1 = 0.f, s2 = 0.f;
  if (t < 192) {
    const short* a = qp + (size_t)row * QLORA + t * 8;
    sx8 u = *(const sx8*)(a);
    sx8 v = *(const sx8*)(a + QS);
    sx8 w = *(const sx8*)(a + 2 * QS);
#pragma unroll
    for (int j = 0; j < 8; ++j) {
      x[j] = bf2f(u[j]) + bf2f(v[j]) + bf2f(w[j]) + q_bias[t * 8 + j];
      s1 += x[j] * x[j];
    }
  } else {
    const int c = t - 192;
    const short* a = kvp + (size_t)row * 576 + c * 8;
    sx8 u = *(const sx8*)(a);
    sx8 v = *(const sx8*)(a + KS);
    sx8 w = *(const sx8*)(a + 2 * KS);
#pragma unroll
    for (int j = 0; j < 8; ++j) {
      x[j] = bf2f(u[j]) + bf2f(v[j]) + bf2f(w[j]) + kv_bias[c * 8 + j];
      s2 += x[j] * x[j];
    }
  }
#pragma unroll
  for (int o = 32; o >= 1; o >>= 1) {
    s1 += __shfl_xor(s1, o, 64);
    s2 += __shfl_xor(s2, o, 64);
  }
  __shared__ float r1[4], r2[4];
  if ((t & 63) == 0) { r1[t >> 6] = s1; r2[t >> 6] = s2; }
  __syncthreads();
  float qss = r1[0] + r1[1] + r1[2] + r1[3];
  float kss = r2[0] + r2[1] + r2[2] + r2[3];
  float qrs = 1.0f / sqrtf(qss / (float)QLORA + 1e-6f);
  float krs = 1.0f / sqrtf(kss / (float)KVLORA + 1e-6f);

  if (t < 192) {
    sx8 o;
#pragma unroll
    for (int j = 0; j < 8; ++j) o[j] = f2bf(x[j] * qrs * q_norm_w[t * 8 + j]);
    *(sx8*)(qn + (size_t)row * QLORA + t * 8) = o;
  } else {
    int c = t - 192;
    sx8 o;
#pragma unroll
    for (int j = 0; j < 8; ++j) o[j] = f2bf(x[j] * krs * kv_norm_w[c * 8 + j]);
    *(sx8*)(kvn + (size_t)row * KVLORA + c * 8) = o;
  }
  if (t < 8) {
    const short* a = kvp + (size_t)row * 576 + 512 + t * 8;
    sx8 u = *(const sx8*)(a);
    sx8 v = *(const sx8*)(a + KS);
    sx8 w = *(const sx8*)(a + 2 * KS);
    float y[8];
#pragma unroll
    for (int j = 0; j < 8; ++j)
      y[j] = bf2f(u[j]) + bf2f(v[j]) + bf2f(w[j]) + kv_bias[512 + t * 8 + j];
    int pos = row & (SS - 1);
    sx8 o;
#pragma unroll
    for (int k = 0; k < 4; ++k) {
      int i = t * 4 + k;
      float c = tab[(pos * 32 + i) * 2], s = tab[(pos * 32 + i) * 2 + 1];
      o[2 * k]     = f2bf(y[2 * k] * c - y[2 * k + 1] * s);
      o[2 * k + 1] = f2bf(y[2 * k] * s + y[2 * k + 1] * c);
    }
    *(sx8*)(kr + (size_t)row * 64 + t * 8) = o;
  }
}

// ---------------- fused post: V-transpose (blocks 0..511) + rope_q ----------
__global__ __launch_bounds__(256)
void k_post(const short* __restrict__ kvb, short* __restrict__ vt,
            short* __restrict__ qb, const float* __restrict__ tab) {
  const int bid = blockIdx.x;
  const int tid = threadIdx.x;
  if (bid < 512) {
    const int bh = bid >> 4;
    const int t0 = (bid & 15) * 64;
    const int b = bh >> 4, h = bh & 15;
    __shared__ short sm[64 * 128];
#pragma unroll
    for (int i = 0; i < 4; ++i) {
      int c = tid + 256 * i;
      int tt = c >> 4, d0 = (c & 15) * 8;
      sx8 v = *(const sx8*)(kvb + ((size_t)(b * SS + t0 + tt)) * 4096 + h * 256 + 128 + d0);
      *(sx8*)(sm + tt * 128 + d0) = v;
    }
    __syncthreads();
#pragma unroll
    for (int i = 0; i < 4; ++i) {
      int c = tid + 256 * i;
      int d = c >> 3, tof = (c & 7) * 8;
      sx8 v;
#pragma unroll
      for (int j = 0; j < 8; ++j) v[j] = sm[(tof + j) * 128 + d];
      *(sx8*)(vt + ((size_t)bh * VH + d) * SS + t0 + tof) = v;
    }
  } else {
    int p = (bid - 512) * 256 + tid;
    int j = p & 7, h = (p >> 3) & 15, row = p >> 7;
    int pos = row & (SS - 1);
    size_t base = (((size_t)row * NHEADS + h) * QKH) + 128 + j * 8;
    sx8 x = *(const sx8*)(qb + base);
    sx8 o;
#pragma unroll
    for (int k = 0; k < 4; ++k) {
      int i = j * 4 + k;
      float c = tab[(pos * 32 + i) * 2], s = tab[(pos * 32 + i) * 2 + 1];
      float x1 = bf2f(x[2 * k]), x2 = bf2f(x[2 * k + 1]);
      o[2 * k]     = f2bf(x1 * c - x2 * s);
      o[2 * k + 1] = f2bf(x1 * s + x2 * c);
    }
    *(sx8*)(qb + base) = o;
  }
}

// ---------------- wo split-K reduce (bf16 partials): out = p0 + p1 + bias ---
__global__ __launch_bounds__(256)
void k_osum(const short* __restrict__ p, const float* __restrict__ bias,
            float* __restrict__ out) {
  const size_t OS = (size_t)2048 * HID;
  int i = blockIdx.x * 256 + threadIdx.x;          // 8-elem chunk index
  sx8 a = *(const sx8*)(p + (size_t)i * 8);
  sx8 b = *(const sx8*)(p + OS + (size_t)i * 8);
  int col = (i * 8) % HID;
  fx4 o0, o1;
#pragma unroll
  for (int j = 0; j < 4; ++j) {
    o0[j] = bf2f(a[j]) + bf2f(b[j]) + bias[col + j];
    o1[j] = bf2f(a[4 + j]) + bf2f(b[4 + j]) + bias[col + 4 + j];
  }
  *(fx4*)(out + (size_t)i * 8) = o0;
  *(fx4*)(out + (size_t)i * 8 + 4) = o1;
}

// ---------------- fused causal attention (balanced q-tile permutation) ------
__global__ __launch_bounds__(256, 2)
void k_attn(const short* __restrict__ q, const short* __restrict__ kvb,
            const short* __restrict__ kr, const short* __restrict__ vt,
            short* __restrict__ ao) {
  const int bh = blockIdx.x;
  const int b = bh >> 4, h = bh & 15;
  // balanced permutation: blocks y and y+8 (co-resident on a CU) get q-tiles
  // summing to a constant 17 K-tiles of work
  const int py = blockIdx.y;
  const int qi = (py < 8) ? py : 23 - py;
  const int qt0 = qi * 64;
  const int tid = threadIdx.x;
  const int lane = tid & 63;
  const int wave = tid >> 6;
  const int g = lane >> 4, r16 = lane & 15;
  const int qg = qt0 + wave * 16 + r16;

  __shared__ short Ks[64 * QKH];
  __shared__ short Vs[VH * 64];

  sx8 qf[6];
  {
    const short* qr = q + (((size_t)(b * SS + qg)) * NHEADS + h) * QKH;
#pragma unroll
    for (int f = 0; f < 6; ++f) qf[f] = ldfrag(qr + f * 32 + 4 * g);
  }

  float mrun = -1e30f, lrun = 0.0f;
  fx4 oacc[8] = {};
  const float scale = 0.07216878364870323f;

  const int ntiles = qt0 / 64 + 1;
  for (int kt = 0; kt < ntiles; ++kt) {
    const int t0 = kt * 64;
#pragma unroll
    for (int i = 0; i < 6; ++i) {
      int cc = tid + 256 * i;
      int row = cc / 24, ch = cc % 24;
      int sc = (ch & 24) | ((ch & 7) ^ (row & 7));
      size_t grow = (size_t)(b * SS + t0 + row);
      const short* src = (sc < 16) ? kvb + grow * 4096 + h * 256 + sc * 8
                                   : kr + grow * 64 + (sc - 16) * 8;
      gl_lds16(src, &Ks[cc * 8]);
    }
#pragma unroll
    for (int i = 0; i < 4; ++i) {
      int cc = tid + 256 * i;
      int row = cc >> 3;
      int sc = (cc & 7) ^ (row & 7);
      gl_lds16(vt + ((size_t)bh * VH + row) * SS + t0 + sc * 8, &Vs[cc * 8]);
    }
    __syncthreads();

    const bool diag = (kt == ntiles - 1);
    float pv[16];
    float tmax = -1e30f;
#pragma unroll
    for (int th = 0; th < 4; ++th) {
      fx4 sacc = {};
#pragma unroll
      for (int f = 0; f < 6; ++f) {
        sx8 kf = ldfrag_swz(Ks, th * 16 + r16, QKH, f * 4, g);
        sacc = __builtin_amdgcn_mfma_f32_16x16x32_bf16(kf, qf[f], sacc, 0, 0, 0);
      }
#pragma unroll
      for (int r = 0; r < 4; ++r) {
        int t = t0 + th * 16 + 4 * g + r;
        float s = sacc[r] * scale;
        if (diag && t > qg) s = -1e30f;
        pv[th * 4 + r] = s;
        tmax = fmaxf(tmax, s);
      }
    }
    tmax = fmaxf(tmax, __shfl_xor(tmax, 16, 64));
    tmax = fmaxf(tmax, __shfl_xor(tmax, 32, 64));
    float mnew = fmaxf(mrun, tmax);
    float corr = __expf(mrun - mnew);
    float psum = 0.f;
#pragma unroll
    for (int j = 0; j < 16; ++j) { pv[j] = __expf(pv[j] - mnew); psum += pv[j]; }
    psum += __shfl_xor(psum, 16, 64);
    psum += __shfl_xor(psum, 32, 64);
    lrun = lrun * corr + psum;
    mrun = mnew;
#pragma unroll
    for (int f8 = 0; f8 < 8; ++f8) oacc[f8] *= corr;

    sx8 pf0, pf1;
#pragma unroll
    for (int j = 0; j < 8; ++j) { pf0[j] = f2bf(pv[j]); pf1[j] = f2bf(pv[8 + j]); }

#pragma unroll
    for (int f8 = 0; f8 < 8; ++f8) {
      sx8 v0 = ldfrag_swz(Vs, f8 * 16 + r16, 64, 0, g);
      sx8 v1 = ldfrag_swz(Vs, f8 * 16 + r16, 64, 4, g);
      oacc[f8] = __builtin_amdgcn_mfma_f32_16x16x32_bf16(v0, pf0, oacc[f8], 0, 0, 0);
      oacc[f8] = __builtin_amdgcn_mfma_f32_16x16x32_bf16(v1, pf1, oacc[f8], 0, 0, 0);
    }
    __syncthreads();
  }

  float inv = 1.0f / lrun;
#pragma unroll
  for (int f8 = 0; f8 < 8; ++f8)
#pragma unroll
    for (int r = 0; r < 4; ++r) {
      int d = f8 * 16 + 4 * g + r;
      ao[(((size_t)(b * SS + qg)) * NHEADS + h) * VH + d] = f2bf(oacc[f8][r] * inv);
    }
}

// ---------------- launcher ----------------
extern "C" void kernel_launch(void* const* d_in, const int* in_sizes, int n_in,
                              void* d_out, int out_size, void* d_ws, size_t ws_size,
                              hipStream_t stream) {
  const float* hs       = (const float*)d_in[0];
  const float* wq_a_w   = (const float*)d_in[2];
  const float* wq_a_b   = (const float*)d_in[3];
  const float* q_norm_w = (const float*)d_in[4];
  const float* wq_b_w   = (const float*)d_in[5];
  const float* wq_b_b   = (const float*)d_in[6];
  const float* wkv_a_w  = (const float*)d_in[7];
  const float* wkv_a_b  = (const float*)d_in[8];
  const float* kv_norm_w= (const float*)d_in[9];
  const float* wkv_b_w  = (const float*)d_in[10];
  const float* wkv_b_b  = (const float*)d_in[11];
  const float* wo_w     = (const float*)d_in[12];
  const float* wo_b     = (const float*)d_in[13];
  float* out = (float*)d_out;

  short* ws0 = (short*)d_ws;
  size_t off = 0;
  short* wqa_bf  = ws0 + off; off += (size_t)QLORA * HID;
  short* wqb_bf  = ws0 + off; off += (size_t)HID * QLORA;
  short* wkva_bf = ws0 + off; off += (size_t)576 * HID;
  short* wkvb_bf = ws0 + off; off += (size_t)4096 * KVLORA;
  short* wo_bf   = ws0 + off; off += (size_t)HID * 2048;
  short* h_bf    = ws0 + off; off += (size_t)MROWS * HID;
  short* qn      = ws0 + off; off += (size_t)MROWS * QLORA;
  short* kvn     = ws0 + off; off += (size_t)MROWS * KVLORA;
  short* kr      = ws0 + off; off += (size_t)MROWS * 64;
  short* qb      = ws0 + off; off += (size_t)MROWS * HID;
  short* kvb     = ws0 + off; off += (size_t)MROWS * 4096;
  short* vtb     = ws0 + off; off += (size_t)BB * NHEADS * VH * SS;
  short* ao      = ws0 + off; off += (size_t)MROWS * 2048;
  float* tab     = (float*)(ws0 + off + (off & 1));
  // bf16 partial arena (time-shared: a-GEMM partials, then wo partials)
  short* arena   = (short*)(tab + SS * 64);
  short* qlatp   = arena;                                  // [3][2048][1536] bf16
  short* kvp     = arena + (size_t)3 * 2048 * QLORA;       // [3][2048][576] bf16
  short* wop     = arena;                                  // [2][2048][3072] bf16

  // 1) cvt {hs, wqa, wkva} + rope table (one launch)
  {
    CvtSeg s0{hs,      h_bf,    (int)((size_t)MROWS * HID / 4)};
    CvtSeg s1{wq_a_w,  wqa_bf,  (int)((size_t)QLORA * HID / 4)};
    CvtSeg s2{wkv_a_w, wkva_bf, (int)((size_t)576 * HID / 4)};
    k_cvt3<<<1024 + 128, 256, 0, stream>>>(s0, s1, s2, tab);
  }

  // 2) merged a-GEMM splitK3 (bf16 partials) + tail cvt of {wqb, wkvb}
  {
    GemmProb pq{h_bf, wqa_bf,  nullptr, qlatp, QLORA, HID};
    GemmProb pk{h_bf, wkva_bf, nullptr, kvp,   576,   HID};
    int nb0 = 8 * (QLORA / 128) * 3;         // 288
    int nb1 = 8 * ((576 + 127) / 128) * 3;   // 120
    int nbG = nb0 + nb1;                     // 408
    CvtSeg c0{wq_b_w,  wqb_bf,  (int)((size_t)HID * QLORA / 4)};
    CvtSeg c1{wkv_b_w, wkvb_bf, (int)((size_t)4096 * KVLORA / 4)};
    k_gemmS<8, 3><<<nbG + 192, 256, 0, stream>>>(pq, pk, nb0, nbG, c0, c1);
  }

  // 3) fused split-K reduce + bias + norms + rope_k
  k_prep<<<MROWS, 256, 0, stream>>>(qlatp, wq_a_b, q_norm_w, qn,
                                    kvp, wkv_a_b, kv_norm_w, kvn, kr, tab);

  // 4) merged b-GEMM + tail cvt of {wo}
  {
    GemmProb pq{qn,  wqb_bf,  wq_b_b,  qb,  HID,  QLORA};
    GemmProb pk{kvn, wkvb_bf, wkv_b_b, kvb, 4096, KVLORA};
    int nb0 = 8 * (HID / 128);               // 192
    int nb1 = 8 * (4096 / 128);              // 256
    int nbG = nb0 + nb1;                     // 448
    CvtSeg c0{wo_w, wo_bf, (int)((size_t)HID * 2048 / 4)};
    CvtSeg c1{nullptr, nullptr, 0};
    k_gemmS<8, 1><<<nbG + 192, 256, 0, stream>>>(pq, pk, nb0, nbG, c0, c1);
  }

  // 5) fused V-transpose + rope_q
  k_post<<<512 + 1024, 256, 0, stream>>>(kvb, vtb, qb, tab);

  // 6) attention (balanced causal work)
  k_attn<<<dim3(BB * NHEADS, SS / 64), 256, 0, stream>>>(qb, kvb, kr, vtb, ao);

  // 7) output projection, split-K x2 (bf16 partials) + fused bias-reduce
  {
    GemmProb po{ao, wo_bf, nullptr, wop, HID, 2048};
    int nb = 8 * (HID / 128) * 2;            // 384
    CvtSeg cz{nullptr, nullptr, 0};
    k_gemmS<8, 2><<<nb, 256, 0, stream>>>(po, po, nb, nb, cz, cz);
  }
  k_osum<<<(MROWS * HID / 8) / 256, 256, 0, stream>>>(wop, wo_b, out);
}